// Round 2
// baseline (181.809 us; speedup 1.0000x reference)
//
#include <hip/hip_runtime.h>

#define B_PAT 32
#define RPP 64
#define RTOT 2048
#define NV 32
#define LMAX 1008
#define NTS 16
#define NIN 64   // K-padded from 34
#define HW 128   // MLP width / hidden
#define LDSP 136 // LDS row stride (pad +8 bf16 to avoid bank conflicts)

typedef __attribute__((ext_vector_type(8))) short short8;
typedef __attribute__((ext_vector_type(4))) float floatx4;

__device__ __forceinline__ ushort f2b(float f) {
  unsigned int x = __float_as_uint(f);
  unsigned int r = (x + 0x7FFFu + ((x >> 16) & 1u)) >> 16;
  return (ushort)r;
}
__device__ __forceinline__ unsigned int pack2(ushort lo, ushort hi) {
  return (unsigned int)lo | ((unsigned int)hi << 16);
}
__device__ __forceinline__ unsigned long long shfl_up_u64(unsigned long long x, int off) {
  int lo = (int)(x & 0xffffffffull), hi = (int)(x >> 32);
  lo = __shfl_up(lo, off); hi = __shfl_up(hi, off);
  return ((unsigned long long)(unsigned int)hi << 32) | (unsigned long long)(unsigned int)lo;
}

// ---------------------------------------------------------------------------
// K1: nonzero scan -> packed per-patient bf16 features (K padded to 64).
// blocks [0,32): patients. block 32: W0 -> bf16 K-padded. 33: W1->bf16. 34: W2->bf16.
// ---------------------------------------------------------------------------
__global__ __launch_bounds__(256) void k1_features(
    const float* __restrict__ times, const int* __restrict__ time_ptr,
    const float* __restrict__ X, const int* __restrict__ M,
    const int* __restrict__ obs_idx, const float* __restrict__ W0,
    const float* __restrict__ W1, const float* __restrict__ W2,
    ushort* __restrict__ feats, ushort* __restrict__ W0p,
    ushort* __restrict__ W1b, ushort* __restrict__ W2b, int* __restrict__ lens)
{
  const int b = blockIdx.x;
  const int t = threadIdx.x;
  if (b == B_PAT) {
    for (int i = t; i < HW * NIN; i += 256) {
      int n = i >> 6, k = i & 63;
      W0p[i] = (k < 34) ? f2b(W0[n * 34 + k]) : (ushort)0;
    }
    return;
  }
  if (b == B_PAT + 1) {
    for (int i = t; i < HW * HW; i += 256) W1b[i] = f2b(W1[i]);
    return;
  }
  if (b == B_PAT + 2) {
    for (int i = t; i < HW * HW; i += 256) W2b[i] = f2b(W2[i]);
    return;
  }
  __shared__ float inv_ts[NTS];
  __shared__ unsigned long long wsum[4];
  __shared__ int rowlist[RPP];
  __shared__ int rowpos[RPP];
  if (t < NTS) {
    float ts = powf(100.0f, (float)t * (1.0f / 15.0f));
    inv_ts[t] = 1.0f / ts;
  }
  const int lane = t & 63, wv = t >> 6;
  // each thread owns 8 consecutive rows; scan (obs count | row-presence<<32)
  unsigned long long acc = 0ull;
  unsigned long long pref[8];
  const int rbase = t * 8;
#pragma unroll
  for (int j = 0; j < 8; ++j) {
    int r = rbase + j;
    int c = 0, pres = 0;
    if (obs_idx[r] == b) {
      pres = 1;
      const int4* mp = (const int4*)(M + r * NV);
#pragma unroll
      for (int q = 0; q < 8; ++q) {
        int4 m4 = mp[q];
        c += (m4.x != 0) + (m4.y != 0) + (m4.z != 0) + (m4.w != 0);
      }
    }
    pref[j] = acc;
    acc += (unsigned long long)(unsigned int)c | ((unsigned long long)pres << 32);
  }
  unsigned long long incl = acc;
  for (int off = 1; off < 64; off <<= 1) {
    unsigned long long v = shfl_up_u64(incl, off);
    if (lane >= off) incl += v;
  }
  if (lane == 63) wsum[wv] = incl;
  __syncthreads();
  unsigned long long wbase = 0ull;
  for (int w = 0; w < wv; ++w) wbase += wsum[w];
  unsigned long long totalall = wsum[0] + wsum[1] + wsum[2] + wsum[3];
  const int total = (int)(totalall & 0xffffffffull);
  const int nrows = (int)(totalall >> 32);
  unsigned long long myexcl = wbase + incl - acc;
#pragma unroll
  for (int j = 0; j < 8; ++j) {
    int r = rbase + j;
    if (obs_idx[r] == b) {
      unsigned long long p = myexcl + pref[j];
      int ord = (int)(p >> 32);
      if (ord < RPP) { rowlist[ord] = r; rowpos[ord] = (int)(p & 0xffffffffull); }
    }
  }
  if (t == 0) lens[b] = total;
  __syncthreads();
  // scatter: 4 threads per patient-row (8 cols each)
  const int o = t >> 2, sub = t & 3;
  if (o < nrows && o < RPP) {
    int r = rowlist[o];
    int base = rowpos[o];
    // generic time_ptr search: k s.t. time_ptr[k] <= r < time_ptr[k+1]
    int lo = 0, hi = RTOT - 1;
    while (lo < hi) { int mid = (lo + hi + 1) >> 1; if (time_ptr[mid] <= r) lo = mid; else hi = mid - 1; }
    float tv = times[lo];
    float sv[NTS], cv[NTS];
#pragma unroll
    for (int i = 0; i < NTS; ++i) {
      float a = tv * inv_ts[i];
      sv[i] = sinf(a); cv[i] = cosf(a);
    }
    int cnt = 0;
    const int cb = sub * 8;
    for (int vv = 0; vv < cb; ++vv) cnt += (M[r * NV + vv] != 0);
    int pos = base + cnt;
    for (int vv = cb; vv < cb + 8; ++vv) {
      if (M[r * NV + vv] != 0) {
        unsigned int* fp = (unsigned int*)(feats + ((size_t)b * LMAX + pos) * NIN);
#pragma unroll
        for (int i = 0; i < 8; ++i) fp[i] = pack2(f2b(sv[2 * i]), f2b(sv[2 * i + 1]));
#pragma unroll
        for (int i = 0; i < 8; ++i) fp[8 + i] = pack2(f2b(cv[2 * i]), f2b(cv[2 * i + 1]));
        fp[16] = pack2(f2b((float)vv), f2b(X[r * NV + vv]));
#pragma unroll
        for (int i = 17; i < 32; ++i) fp[i] = 0u;
        ++pos;
      }
    }
  }
  // pad fill: [total, LMAX) gets [0 x16 | 1.0 x16 | 0,0 | 0...]
  {
    uint4 z = make_uint4(0u, 0u, 0u, 0u);
    uint4 one; one.x = one.y = one.z = one.w = 0x3F803F80u;
    for (int pos = total + t; pos < LMAX; pos += 256) {
      uint4* fp = (uint4*)(feats + ((size_t)b * LMAX + pos) * NIN);
      fp[0] = z; fp[1] = z; fp[2] = one; fp[3] = one;
      fp[4] = z; fp[5] = z; fp[6] = z; fp[7] = z;
    }
  }
}

// ---------------------------------------------------------------------------
// K2: fused 3-layer MLP via MFMA bf16 16x16x32, fp32 accum + fp32 enc out.
// Block = 64 rows, 4 waves; wave handles 16 rows x 128 cols.
// ---------------------------------------------------------------------------
__global__ __launch_bounds__(256) void k2_mlp(
    const ushort* __restrict__ feats, const ushort* __restrict__ W0p,
    const float* __restrict__ b0, const ushort* __restrict__ W1b,
    const float* __restrict__ b1, const ushort* __restrict__ W2b,
    const float* __restrict__ b2, float* __restrict__ enc)
{
  __shared__ ushort bufA[64 * LDSP];
  __shared__ ushort bufB[64 * LDSP];
  const int tid = threadIdx.x;
  const int wv = tid >> 6, lane = tid & 63;
  const int m16 = lane & 15, quad = lane >> 4;
  const int rowl = wv * 16 + m16;
  const size_t grow = (size_t)blockIdx.x * 64;
  // ---- layer 0: feats[.,64] @ W0p^T  (K=64)
  {
    const short8* ar = (const short8*)(feats + (grow + rowl) * NIN);
    short8 a0 = ar[quad];
    short8 a1 = ar[4 + quad];
#pragma unroll
    for (int nt = 0; nt < 8; ++nt) {
      int n = nt * 16 + m16;
      const short8* br = (const short8*)(W0p + n * NIN);
      floatx4 acc = {0.f, 0.f, 0.f, 0.f};
      acc = __builtin_amdgcn_mfma_f32_16x16x32_bf16(a0, br[quad], acc, 0, 0, 0);
      acc = __builtin_amdgcn_mfma_f32_16x16x32_bf16(a1, br[4 + quad], acc, 0, 0, 0);
      float bias = b0[n];
#pragma unroll
      for (int i = 0; i < 4; ++i) {
        float vv = fmaxf(acc[i] + bias, 0.0f);
        bufA[(wv * 16 + quad * 4 + i) * LDSP + n] = f2b(vv);
      }
    }
  }
  __syncthreads();
  // ---- layer 1: h0 @ W1^T (K=128)
  {
#pragma unroll
    for (int nt = 0; nt < 8; ++nt) {
      int n = nt * 16 + m16;
      floatx4 acc = {0.f, 0.f, 0.f, 0.f};
#pragma unroll
      for (int ks = 0; ks < 4; ++ks) {
        short8 a = *(const short8*)(bufA + rowl * LDSP + ks * 32 + quad * 8);
        short8 bb = *(const short8*)(W1b + n * HW + ks * 32 + quad * 8);
        acc = __builtin_amdgcn_mfma_f32_16x16x32_bf16(a, bb, acc, 0, 0, 0);
      }
      float bias = b1[n];
#pragma unroll
      for (int i = 0; i < 4; ++i) {
        float vv = fmaxf(acc[i] + bias, 0.0f);
        bufB[(wv * 16 + quad * 4 + i) * LDSP + n] = f2b(vv);
      }
    }
  }
  __syncthreads();
  // ---- layer 2: h1 @ W2^T + b2 -> enc (fp32, global)
  {
#pragma unroll
    for (int nt = 0; nt < 8; ++nt) {
      int n = nt * 16 + m16;
      floatx4 acc = {0.f, 0.f, 0.f, 0.f};
#pragma unroll
      for (int ks = 0; ks < 4; ++ks) {
        short8 a = *(const short8*)(bufB + rowl * LDSP + ks * 32 + quad * 8);
        short8 bb = *(const short8*)(W2b + n * HW + ks * 32 + quad * 8);
        acc = __builtin_amdgcn_mfma_f32_16x16x32_bf16(a, bb, acc, 0, 0, 0);
      }
      float bias = b2[n];
#pragma unroll
      for (int i = 0; i < 4; ++i) {
        enc[(grow + wv * 16 + quad * 4 + i) * HW + n] = acc[i] + bias;
      }
    }
  }
}

// ---------------------------------------------------------------------------
// K3: attention for the last-row query only (fp32). bk dropped
// (constant-in-m logit shift -> softmax invariant). Block = one patient.
// ---------------------------------------------------------------------------
__global__ __launch_bounds__(256) void k3_attn(
    const float* __restrict__ enc, const int* __restrict__ lens,
    const float* __restrict__ Wq, const float* __restrict__ bq,
    const float* __restrict__ Wk, float* __restrict__ out)
{
  const int b = blockIdx.x;
  const int tid = threadIdx.x;
  __shared__ float encq_s[HW];
  __shared__ float q_s[HW];
  __shared__ float r_s[4 * HW];
  __shared__ float logit[4 * LMAX];
  __shared__ float sm_s[4];
  const int len = lens[b];
  const float* encb = enc + (size_t)b * LMAX * HW;
  if (tid < HW) encq_s[tid] = encb[(LMAX - 1) * HW + tid];
  __syncthreads();
  // q = Wq @ enc_q + bq
  if (tid < HW) {
    float acc = bq[tid];
    const float4* wr = (const float4*)(Wq + tid * HW);
#pragma unroll 8
    for (int e4 = 0; e4 < 32; ++e4) {
      float4 w4 = wr[e4];
      acc += w4.x * encq_s[e4 * 4 + 0] + w4.y * encq_s[e4 * 4 + 1] +
             w4.z * encq_s[e4 * 4 + 2] + w4.w * encq_s[e4 * 4 + 3];
    }
    q_s[tid] = acc;
  }
  __syncthreads();
  // r[h][e] = (Wk_h^T q_h)[e] / sqrt(32)
  const float scale = 0.17677669529663687f;
  for (int idx = tid; idx < 4 * HW; idx += 256) {
    int h = idx >> 7, e = idx & 127;
    float acc = 0.f;
#pragma unroll 8
    for (int d = 0; d < 32; ++d) acc += Wk[(h * 32 + d) * HW + e] * q_s[h * 32 + d];
    r_s[idx] = acc * scale;
  }
  __syncthreads();
  // logits for all 4 heads
  for (int m = tid; m < len; m += 256) {
    const float4* er = (const float4*)(encb + (size_t)m * HW);
    float a0 = 0.f, a1 = 0.f, a2 = 0.f, a3 = 0.f;
#pragma unroll 4
    for (int e4 = 0; e4 < 32; ++e4) {
      float4 v4 = er[e4];
      int e = e4 * 4;
      a0 += r_s[e] * v4.x + r_s[e + 1] * v4.y + r_s[e + 2] * v4.z + r_s[e + 3] * v4.w;
      a1 += r_s[HW + e] * v4.x + r_s[HW + e + 1] * v4.y + r_s[HW + e + 2] * v4.z + r_s[HW + e + 3] * v4.w;
      a2 += r_s[2 * HW + e] * v4.x + r_s[2 * HW + e + 1] * v4.y + r_s[2 * HW + e + 2] * v4.z + r_s[2 * HW + e + 3] * v4.w;
      a3 += r_s[3 * HW + e] * v4.x + r_s[3 * HW + e + 1] * v4.y + r_s[3 * HW + e + 2] * v4.z + r_s[3 * HW + e + 3] * v4.w;
    }
    logit[m] = a0; logit[LMAX + m] = a1; logit[2 * LMAX + m] = a2; logit[3 * LMAX + m] = a3;
  }
  __syncthreads();
  // softmax per head: wave h handles head h
  {
    const int wv = tid >> 6, lane = tid & 63;
    float mx = -1e30f;
    for (int m = lane; m < len; m += 64) mx = fmaxf(mx, logit[wv * LMAX + m]);
#pragma unroll
    for (int o = 32; o >= 1; o >>= 1) mx = fmaxf(mx, __shfl_xor(mx, o));
    float sm = 0.f;
    for (int m = lane; m < len; m += 64) {
      float p = expf(logit[wv * LMAX + m] - mx);
      logit[wv * LMAX + m] = p;
      sm += p;
    }
#pragma unroll
    for (int o = 32; o >= 1; o >>= 1) sm += __shfl_xor(sm, o);
    if (lane == 0) sm_s[wv] = sm;
  }
  __syncthreads();
  // out[b, h*128+e] = sum_m p[h][m] * enc[m][e] / sm[h]
  {
    const int e = tid & 127, h0 = tid >> 7; // h0 in {0,1}; also do h0+2
    float a0 = 0.f, a1 = 0.f;
    for (int m = 0; m < len; ++m) {
      float v = encb[(size_t)m * HW + e];
      a0 += logit[h0 * LMAX + m] * v;
      a1 += logit[(h0 + 2) * LMAX + m] * v;
    }
    out[b * 512 + h0 * HW + e] = a0 / sm_s[h0];
    out[b * 512 + (h0 + 2) * HW + e] = a1 / sm_s[h0 + 2];
  }
}

extern "C" void kernel_launch(void* const* d_in, const int* in_sizes, int n_in,
                              void* d_out, int out_size, void* d_ws, size_t ws_size,
                              hipStream_t stream) {
  const float* times = (const float*)d_in[0];
  const int* time_ptr = (const int*)d_in[1];
  const float* X = (const float*)d_in[2];
  const int* M = (const int*)d_in[3];
  const int* obs_idx = (const int*)d_in[4];
  const float* W0 = (const float*)d_in[6];
  const float* b0 = (const float*)d_in[7];
  const float* W1 = (const float*)d_in[8];
  const float* b1 = (const float*)d_in[9];
  const float* W2 = (const float*)d_in[10];
  const float* b2 = (const float*)d_in[11];
  const float* Wq = (const float*)d_in[12];
  const float* bq = (const float*)d_in[13];
  const float* Wk = (const float*)d_in[14];
  // d_in[15] (bk) is softmax-invariant for the scores -> dropped.
  float* out = (float*)d_out;

  char* ws = (char*)d_ws;
  size_t off = 0;
  ushort* feats = (ushort*)(ws + off); off += (size_t)B_PAT * LMAX * NIN * sizeof(ushort); // 4.1 MB
  ushort* W0p = (ushort*)(ws + off); off += (size_t)HW * NIN * sizeof(ushort);
  ushort* W1b = (ushort*)(ws + off); off += (size_t)HW * HW * sizeof(ushort);
  ushort* W2b = (ushort*)(ws + off); off += (size_t)HW * HW * sizeof(ushort);
  off = (off + 255) & ~(size_t)255;
  int* lens = (int*)(ws + off); off += 256;
  float* enc = (float*)(ws + off); // 32*1008*128 fp32 = 16.5 MB

  k1_features<<<B_PAT + 3, 256, 0, stream>>>(times, time_ptr, X, M, obs_idx,
                                             W0, W1, W2, feats, W0p, W1b, W2b, lens);
  k2_mlp<<<(B_PAT * LMAX) / 64, 256, 0, stream>>>(feats, W0p, b0, W1b, b1, W2b, b2, enc);
  k3_attn<<<B_PAT, 256, 0, stream>>>(enc, lens, Wq, bq, Wk, out);
}

// Round 3
// 175.687 us; speedup vs baseline: 1.0348x; 1.0348x over previous
//
#include <hip/hip_runtime.h>

#define B_PAT 32
#define RPP 64
#define RTOT 2048
#define NV 32
#define LMAX 1008
#define NTS 16
#define NIN 64   // K-padded from 34
#define HW 128   // MLP width / hidden
#define LDSP 136 // LDS row stride (pad +8 bf16 to avoid bank conflicts)

typedef __attribute__((ext_vector_type(8))) short short8;
typedef __attribute__((ext_vector_type(4))) float floatx4;

__device__ __forceinline__ ushort f2b(float f) {
  unsigned int x = __float_as_uint(f);
  unsigned int r = (x + 0x7FFFu + ((x >> 16) & 1u)) >> 16;
  return (ushort)r;
}
__device__ __forceinline__ unsigned int pack2(ushort lo, ushort hi) {
  return (unsigned int)lo | ((unsigned int)hi << 16);
}
__device__ __forceinline__ unsigned long long shfl_up_u64(unsigned long long x, int off) {
  int lo = (int)(x & 0xffffffffull), hi = (int)(x >> 32);
  lo = __shfl_up(lo, off); hi = __shfl_up(hi, off);
  return ((unsigned long long)(unsigned int)hi << 32) | (unsigned long long)(unsigned int)lo;
}

// ---------------------------------------------------------------------------
// K1: nonzero scan -> packed per-patient bf16 features (K padded to 64).
// blocks [0,32): patients. block 32: W0 -> bf16 K-padded. 33: W1->bf16. 34: W2->bf16.
// ---------------------------------------------------------------------------
__global__ __launch_bounds__(256) void k1_features(
    const float* __restrict__ times, const int* __restrict__ time_ptr,
    const float* __restrict__ X, const int* __restrict__ M,
    const int* __restrict__ obs_idx, const float* __restrict__ W0,
    const float* __restrict__ W1, const float* __restrict__ W2,
    ushort* __restrict__ feats, ushort* __restrict__ W0p,
    ushort* __restrict__ W1b, ushort* __restrict__ W2b, int* __restrict__ lens)
{
  const int b = blockIdx.x;
  const int t = threadIdx.x;
  if (b == B_PAT) {
    for (int i = t; i < HW * NIN; i += 256) {
      int n = i >> 6, k = i & 63;
      W0p[i] = (k < 34) ? f2b(W0[n * 34 + k]) : (ushort)0;
    }
    return;
  }
  if (b == B_PAT + 1) {
    for (int i = t; i < HW * HW; i += 256) W1b[i] = f2b(W1[i]);
    return;
  }
  if (b == B_PAT + 2) {
    for (int i = t; i < HW * HW; i += 256) W2b[i] = f2b(W2[i]);
    return;
  }
  __shared__ float inv_ts[NTS];
  __shared__ unsigned long long wsum[4];
  __shared__ int rowlist[RPP];
  __shared__ int rowpos[RPP];
  if (t < NTS) {
    float ts = powf(100.0f, (float)t * (1.0f / 15.0f));
    inv_ts[t] = 1.0f / ts;
  }
  const int lane = t & 63, wv = t >> 6;
  // each thread owns 8 consecutive rows; scan (obs count | row-presence<<32)
  unsigned long long acc = 0ull;
  unsigned long long pref[8];
  const int rbase = t * 8;
#pragma unroll
  for (int j = 0; j < 8; ++j) {
    int r = rbase + j;
    int c = 0, pres = 0;
    if (obs_idx[r] == b) {
      pres = 1;
      const int4* mp = (const int4*)(M + r * NV);
#pragma unroll
      for (int q = 0; q < 8; ++q) {
        int4 m4 = mp[q];
        c += (m4.x != 0) + (m4.y != 0) + (m4.z != 0) + (m4.w != 0);
      }
    }
    pref[j] = acc;
    acc += (unsigned long long)(unsigned int)c | ((unsigned long long)pres << 32);
  }
  unsigned long long incl = acc;
  for (int off = 1; off < 64; off <<= 1) {
    unsigned long long v = shfl_up_u64(incl, off);
    if (lane >= off) incl += v;
  }
  if (lane == 63) wsum[wv] = incl;
  __syncthreads();
  unsigned long long wbase = 0ull;
  for (int w = 0; w < wv; ++w) wbase += wsum[w];
  unsigned long long totalall = wsum[0] + wsum[1] + wsum[2] + wsum[3];
  const int total = (int)(totalall & 0xffffffffull);
  const int nrows = (int)(totalall >> 32);
  unsigned long long myexcl = wbase + incl - acc;
#pragma unroll
  for (int j = 0; j < 8; ++j) {
    int r = rbase + j;
    if (obs_idx[r] == b) {
      unsigned long long p = myexcl + pref[j];
      int ord = (int)(p >> 32);
      if (ord < RPP) { rowlist[ord] = r; rowpos[ord] = (int)(p & 0xffffffffull); }
    }
  }
  if (t == 0) lens[b] = total;
  __syncthreads();
  // scatter: 4 threads per patient-row (8 cols each)
  const int o = t >> 2, sub = t & 3;
  if (o < nrows && o < RPP) {
    int r = rowlist[o];
    int base = rowpos[o];
    // generic time_ptr search: k s.t. time_ptr[k] <= r < time_ptr[k+1]
    int lo = 0, hi = RTOT - 1;
    while (lo < hi) { int mid = (lo + hi + 1) >> 1; if (time_ptr[mid] <= r) lo = mid; else hi = mid - 1; }
    float tv = times[lo];
    float sv[NTS], cv[NTS];
#pragma unroll
    for (int i = 0; i < NTS; ++i) {
      float a = tv * inv_ts[i];
      sv[i] = sinf(a); cv[i] = cosf(a);
    }
    int cnt = 0;
    const int cb = sub * 8;
    for (int vv = 0; vv < cb; ++vv) cnt += (M[r * NV + vv] != 0);
    int pos = base + cnt;
    for (int vv = cb; vv < cb + 8; ++vv) {
      if (M[r * NV + vv] != 0) {
        unsigned int* fp = (unsigned int*)(feats + ((size_t)b * LMAX + pos) * NIN);
#pragma unroll
        for (int i = 0; i < 8; ++i) fp[i] = pack2(f2b(sv[2 * i]), f2b(sv[2 * i + 1]));
#pragma unroll
        for (int i = 0; i < 8; ++i) fp[8 + i] = pack2(f2b(cv[2 * i]), f2b(cv[2 * i + 1]));
        fp[16] = pack2(f2b((float)vv), f2b(X[r * NV + vv]));
#pragma unroll
        for (int i = 17; i < 32; ++i) fp[i] = 0u;
        ++pos;
      }
    }
  }
  // pad fill: [total, LMAX) gets [0 x16 | 1.0 x16 | 0,0 | 0...]
  {
    uint4 z = make_uint4(0u, 0u, 0u, 0u);
    uint4 one; one.x = one.y = one.z = one.w = 0x3F803F80u;
    for (int pos = total + t; pos < LMAX; pos += 256) {
      uint4* fp = (uint4*)(feats + ((size_t)b * LMAX + pos) * NIN);
      fp[0] = z; fp[1] = z; fp[2] = one; fp[3] = one;
      fp[4] = z; fp[5] = z; fp[6] = z; fp[7] = z;
    }
  }
}

// ---------------------------------------------------------------------------
// K2: fused 3-layer MLP via MFMA bf16 16x16x32, fp32 accum + fp32 enc out.
// Block = 64 rows, 4 waves; wave handles 16 rows x 128 cols.
// ---------------------------------------------------------------------------
__global__ __launch_bounds__(256) void k2_mlp(
    const ushort* __restrict__ feats, const ushort* __restrict__ W0p,
    const float* __restrict__ b0, const ushort* __restrict__ W1b,
    const float* __restrict__ b1, const ushort* __restrict__ W2b,
    const float* __restrict__ b2, float* __restrict__ enc)
{
  __shared__ ushort bufA[64 * LDSP];
  __shared__ ushort bufB[64 * LDSP];
  const int tid = threadIdx.x;
  const int wv = tid >> 6, lane = tid & 63;
  const int m16 = lane & 15, quad = lane >> 4;
  const int rowl = wv * 16 + m16;
  const size_t grow = (size_t)blockIdx.x * 64;
  // ---- layer 0: feats[.,64] @ W0p^T  (K=64)
  {
    const short8* ar = (const short8*)(feats + (grow + rowl) * NIN);
    short8 a0 = ar[quad];
    short8 a1 = ar[4 + quad];
#pragma unroll
    for (int nt = 0; nt < 8; ++nt) {
      int n = nt * 16 + m16;
      const short8* br = (const short8*)(W0p + n * NIN);
      floatx4 acc = {0.f, 0.f, 0.f, 0.f};
      acc = __builtin_amdgcn_mfma_f32_16x16x32_bf16(a0, br[quad], acc, 0, 0, 0);
      acc = __builtin_amdgcn_mfma_f32_16x16x32_bf16(a1, br[4 + quad], acc, 0, 0, 0);
      float bias = b0[n];
#pragma unroll
      for (int i = 0; i < 4; ++i) {
        float vv = fmaxf(acc[i] + bias, 0.0f);
        bufA[(wv * 16 + quad * 4 + i) * LDSP + n] = f2b(vv);
      }
    }
  }
  __syncthreads();
  // ---- layer 1: h0 @ W1^T (K=128)
  {
#pragma unroll
    for (int nt = 0; nt < 8; ++nt) {
      int n = nt * 16 + m16;
      floatx4 acc = {0.f, 0.f, 0.f, 0.f};
#pragma unroll
      for (int ks = 0; ks < 4; ++ks) {
        short8 a = *(const short8*)(bufA + rowl * LDSP + ks * 32 + quad * 8);
        short8 bb = *(const short8*)(W1b + n * HW + ks * 32 + quad * 8);
        acc = __builtin_amdgcn_mfma_f32_16x16x32_bf16(a, bb, acc, 0, 0, 0);
      }
      float bias = b1[n];
#pragma unroll
      for (int i = 0; i < 4; ++i) {
        float vv = fmaxf(acc[i] + bias, 0.0f);
        bufB[(wv * 16 + quad * 4 + i) * LDSP + n] = f2b(vv);
      }
    }
  }
  __syncthreads();
  // ---- layer 2: h1 @ W2^T + b2 -> enc (fp32, global)
  {
#pragma unroll
    for (int nt = 0; nt < 8; ++nt) {
      int n = nt * 16 + m16;
      floatx4 acc = {0.f, 0.f, 0.f, 0.f};
#pragma unroll
      for (int ks = 0; ks < 4; ++ks) {
        short8 a = *(const short8*)(bufB + rowl * LDSP + ks * 32 + quad * 8);
        short8 bb = *(const short8*)(W2b + n * HW + ks * 32 + quad * 8);
        acc = __builtin_amdgcn_mfma_f32_16x16x32_bf16(a, bb, acc, 0, 0, 0);
      }
      float bias = b2[n];
#pragma unroll
      for (int i = 0; i < 4; ++i) {
        enc[(grow + wv * 16 + quad * 4 + i) * HW + n] = acc[i] + bias;
      }
    }
  }
}

// ---------------------------------------------------------------------------
// K3: attention for the last-row query only (fp32). bk dropped
// (constant-in-m logit shift -> softmax invariant). Block = one patient.
// Weighted-sum phase is m-parallel (4 m-groups x 64 lanes, float2/lane).
// ---------------------------------------------------------------------------
__global__ __launch_bounds__(256) void k3_attn(
    const float* __restrict__ enc, const int* __restrict__ lens,
    const float* __restrict__ Wq, const float* __restrict__ bq,
    const float* __restrict__ Wk, float* __restrict__ out)
{
  const int b = blockIdx.x;
  const int tid = threadIdx.x;
  __shared__ float encq_s[HW];
  __shared__ float q_s[HW];
  __shared__ float r_s[4 * HW];
  __shared__ float logit[4 * LMAX];
  __shared__ float sm_s[4];
  __shared__ float red[4][4][HW]; // [m-group][head][e]
  const int len = lens[b];
  const float* encb = enc + (size_t)b * LMAX * HW;
  if (tid < HW) encq_s[tid] = encb[(LMAX - 1) * HW + tid];
  __syncthreads();
  // q = Wq @ enc_q + bq
  if (tid < HW) {
    float acc = bq[tid];
    const float4* wr = (const float4*)(Wq + tid * HW);
#pragma unroll 8
    for (int e4 = 0; e4 < 32; ++e4) {
      float4 w4 = wr[e4];
      acc += w4.x * encq_s[e4 * 4 + 0] + w4.y * encq_s[e4 * 4 + 1] +
             w4.z * encq_s[e4 * 4 + 2] + w4.w * encq_s[e4 * 4 + 3];
    }
    q_s[tid] = acc;
  }
  __syncthreads();
  // r[h][e] = (Wk_h^T q_h)[e] / sqrt(32)
  const float scale = 0.17677669529663687f;
  for (int idx = tid; idx < 4 * HW; idx += 256) {
    int h = idx >> 7, e = idx & 127;
    float acc = 0.f;
#pragma unroll 8
    for (int d = 0; d < 32; ++d) acc += Wk[(h * 32 + d) * HW + e] * q_s[h * 32 + d];
    r_s[idx] = acc * scale;
  }
  __syncthreads();
  // logits for all 4 heads (thread-per-m; ~4 m per thread, float4 ILP)
  for (int m = tid; m < len; m += 256) {
    const float4* er = (const float4*)(encb + (size_t)m * HW);
    float a0 = 0.f, a1 = 0.f, a2 = 0.f, a3 = 0.f;
#pragma unroll 8
    for (int e4 = 0; e4 < 32; ++e4) {
      float4 v4 = er[e4];
      int e = e4 * 4;
      a0 += r_s[e] * v4.x + r_s[e + 1] * v4.y + r_s[e + 2] * v4.z + r_s[e + 3] * v4.w;
      a1 += r_s[HW + e] * v4.x + r_s[HW + e + 1] * v4.y + r_s[HW + e + 2] * v4.z + r_s[HW + e + 3] * v4.w;
      a2 += r_s[2 * HW + e] * v4.x + r_s[2 * HW + e + 1] * v4.y + r_s[2 * HW + e + 2] * v4.z + r_s[2 * HW + e + 3] * v4.w;
      a3 += r_s[3 * HW + e] * v4.x + r_s[3 * HW + e + 1] * v4.y + r_s[3 * HW + e + 2] * v4.z + r_s[3 * HW + e + 3] * v4.w;
    }
    logit[m] = a0; logit[LMAX + m] = a1; logit[2 * LMAX + m] = a2; logit[3 * LMAX + m] = a3;
  }
  __syncthreads();
  // softmax per head: wave h handles head h
  {
    const int wv = tid >> 6, lane = tid & 63;
    float mx = -1e30f;
    for (int m = lane; m < len; m += 64) mx = fmaxf(mx, logit[wv * LMAX + m]);
#pragma unroll
    for (int o = 32; o >= 1; o >>= 1) mx = fmaxf(mx, __shfl_xor(mx, o));
    float sm = 0.f;
    for (int m = lane; m < len; m += 64) {
      float p = expf(logit[wv * LMAX + m] - mx);
      logit[wv * LMAX + m] = p;
      sm += p;
    }
#pragma unroll
    for (int o = 32; o >= 1; o >>= 1) sm += __shfl_xor(sm, o);
    if (lane == 0) sm_s[wv] = sm;
  }
  __syncthreads();
  // weighted sum, m-parallel: thread = (ms, lane); lane owns e-pair (float2).
  // acc[h][0..1] over m in {ms, ms+4, ...}; then 4-way LDS reduce.
  {
    const int ms = tid >> 6, lane = tid & 63;
    const int e0 = lane * 2;
    float acc00 = 0.f, acc01 = 0.f, acc10 = 0.f, acc11 = 0.f;
    float acc20 = 0.f, acc21 = 0.f, acc30 = 0.f, acc31 = 0.f;
#pragma unroll 4
    for (int m = ms; m < len; m += 4) {
      float2 v = *(const float2*)(encb + (size_t)m * HW + e0);
      float p0 = logit[m];
      float p1 = logit[LMAX + m];
      float p2 = logit[2 * LMAX + m];
      float p3 = logit[3 * LMAX + m];
      acc00 += p0 * v.x; acc01 += p0 * v.y;
      acc10 += p1 * v.x; acc11 += p1 * v.y;
      acc20 += p2 * v.x; acc21 += p2 * v.y;
      acc30 += p3 * v.x; acc31 += p3 * v.y;
    }
    red[ms][0][e0] = acc00; red[ms][0][e0 + 1] = acc01;
    red[ms][1][e0] = acc10; red[ms][1][e0 + 1] = acc11;
    red[ms][2][e0] = acc20; red[ms][2][e0 + 1] = acc21;
    red[ms][3][e0] = acc30; red[ms][3][e0 + 1] = acc31;
  }
  __syncthreads();
  // final reduce: 512 outputs (4 heads x 128 e), 2 per thread
  for (int idx = tid; idx < 4 * HW; idx += 256) {
    int h = idx >> 7, e = idx & 127;
    float s = red[0][h][e] + red[1][h][e] + red[2][h][e] + red[3][h][e];
    out[b * 512 + h * HW + e] = s / sm_s[h];
  }
}

extern "C" void kernel_launch(void* const* d_in, const int* in_sizes, int n_in,
                              void* d_out, int out_size, void* d_ws, size_t ws_size,
                              hipStream_t stream) {
  const float* times = (const float*)d_in[0];
  const int* time_ptr = (const int*)d_in[1];
  const float* X = (const float*)d_in[2];
  const int* M = (const int*)d_in[3];
  const int* obs_idx = (const int*)d_in[4];
  const float* W0 = (const float*)d_in[6];
  const float* b0 = (const float*)d_in[7];
  const float* W1 = (const float*)d_in[8];
  const float* b1 = (const float*)d_in[9];
  const float* W2 = (const float*)d_in[10];
  const float* b2 = (const float*)d_in[11];
  const float* Wq = (const float*)d_in[12];
  const float* bq = (const float*)d_in[13];
  const float* Wk = (const float*)d_in[14];
  // d_in[15] (bk) is softmax-invariant for the scores -> dropped.
  float* out = (float*)d_out;

  char* ws = (char*)d_ws;
  size_t off = 0;
  ushort* feats = (ushort*)(ws + off); off += (size_t)B_PAT * LMAX * NIN * sizeof(ushort); // 4.1 MB
  ushort* W0p = (ushort*)(ws + off); off += (size_t)HW * NIN * sizeof(ushort);
  ushort* W1b = (ushort*)(ws + off); off += (size_t)HW * HW * sizeof(ushort);
  ushort* W2b = (ushort*)(ws + off); off += (size_t)HW * HW * sizeof(ushort);
  off = (off + 255) & ~(size_t)255;
  int* lens = (int*)(ws + off); off += 256;
  float* enc = (float*)(ws + off); // 32*1008*128 fp32 = 16.5 MB

  k1_features<<<B_PAT + 3, 256, 0, stream>>>(times, time_ptr, X, M, obs_idx,
                                             W0, W1, W2, feats, W0p, W1b, W2b, lens);
  k2_mlp<<<(B_PAT * LMAX) / 64, 256, 0, stream>>>(feats, W0p, b0, W1b, b1, W2b, b2, enc);
  k3_attn<<<B_PAT, 256, 0, stream>>>(enc, lens, Wq, bq, Wk, out);
}

// Round 4
// 157.673 us; speedup vs baseline: 1.1531x; 1.1143x over previous
//
#include <hip/hip_runtime.h>

#define B_PAT 32
#define RPP 64
#define RTOT 2048
#define NV 32
#define LMAX 1008
#define NTS 16
#define NIN 64   // K-padded from 34
#define HW 128   // MLP width / hidden
#define LDSP 136 // LDS row stride for k2 (pad +8 bf16)
#define NCH 16   // attention m-chunks per patient
#define CH 63    // m per chunk (16*63 = 1008)
#define ELD 132  // enc LDS stride (floats), conflict-free & float4-aligned
#define RLD 136  // r LDS stride (floats)

typedef __attribute__((ext_vector_type(8))) short short8;
typedef __attribute__((ext_vector_type(4))) float floatx4;

__device__ __forceinline__ ushort f2b(float f) {
  unsigned int x = __float_as_uint(f);
  unsigned int r = (x + 0x7FFFu + ((x >> 16) & 1u)) >> 16;
  return (ushort)r;
}
__device__ __forceinline__ unsigned int pack2(ushort lo, ushort hi) {
  return (unsigned int)lo | ((unsigned int)hi << 16);
}
__device__ __forceinline__ unsigned long long shfl_up_u64(unsigned long long x, int off) {
  int lo = (int)(x & 0xffffffffull), hi = (int)(x >> 32);
  lo = __shfl_up(lo, off); hi = __shfl_up(hi, off);
  return ((unsigned long long)(unsigned int)hi << 32) | (unsigned long long)(unsigned int)lo;
}

// ---------------------------------------------------------------------------
// K1: nonzero scan -> packed per-patient bf16 features (K padded to 64).
// blocks [0,32): patients. block 32: W0 -> bf16 K-padded. 33: W1->bf16. 34: W2->bf16.
// ---------------------------------------------------------------------------
__global__ __launch_bounds__(256) void k1_features(
    const float* __restrict__ times, const int* __restrict__ time_ptr,
    const float* __restrict__ X, const int* __restrict__ M,
    const int* __restrict__ obs_idx, const float* __restrict__ W0,
    const float* __restrict__ W1, const float* __restrict__ W2,
    ushort* __restrict__ feats, ushort* __restrict__ W0p,
    ushort* __restrict__ W1b, ushort* __restrict__ W2b, int* __restrict__ lens)
{
  const int b = blockIdx.x;
  const int t = threadIdx.x;
  if (b == B_PAT) {
    for (int i = t; i < HW * NIN; i += 256) {
      int n = i >> 6, k = i & 63;
      W0p[i] = (k < 34) ? f2b(W0[n * 34 + k]) : (ushort)0;
    }
    return;
  }
  if (b == B_PAT + 1) {
    for (int i = t; i < HW * HW; i += 256) W1b[i] = f2b(W1[i]);
    return;
  }
  if (b == B_PAT + 2) {
    for (int i = t; i < HW * HW; i += 256) W2b[i] = f2b(W2[i]);
    return;
  }
  __shared__ float inv_ts[NTS];
  __shared__ unsigned long long wsum[4];
  __shared__ int rowlist[RPP];
  __shared__ int rowpos[RPP];
  if (t < NTS) {
    float ts = powf(100.0f, (float)t * (1.0f / 15.0f));
    inv_ts[t] = 1.0f / ts;
  }
  const int lane = t & 63, wv = t >> 6;
  unsigned long long acc = 0ull;
  unsigned long long pref[8];
  const int rbase = t * 8;
#pragma unroll
  for (int j = 0; j < 8; ++j) {
    int r = rbase + j;
    int c = 0, pres = 0;
    if (obs_idx[r] == b) {
      pres = 1;
      const int4* mp = (const int4*)(M + r * NV);
#pragma unroll
      for (int q = 0; q < 8; ++q) {
        int4 m4 = mp[q];
        c += (m4.x != 0) + (m4.y != 0) + (m4.z != 0) + (m4.w != 0);
      }
    }
    pref[j] = acc;
    acc += (unsigned long long)(unsigned int)c | ((unsigned long long)pres << 32);
  }
  unsigned long long incl = acc;
  for (int off = 1; off < 64; off <<= 1) {
    unsigned long long v = shfl_up_u64(incl, off);
    if (lane >= off) incl += v;
  }
  if (lane == 63) wsum[wv] = incl;
  __syncthreads();
  unsigned long long wbase = 0ull;
  for (int w = 0; w < wv; ++w) wbase += wsum[w];
  unsigned long long totalall = wsum[0] + wsum[1] + wsum[2] + wsum[3];
  const int total = (int)(totalall & 0xffffffffull);
  const int nrows = (int)(totalall >> 32);
  unsigned long long myexcl = wbase + incl - acc;
#pragma unroll
  for (int j = 0; j < 8; ++j) {
    int r = rbase + j;
    if (obs_idx[r] == b) {
      unsigned long long p = myexcl + pref[j];
      int ord = (int)(p >> 32);
      if (ord < RPP) { rowlist[ord] = r; rowpos[ord] = (int)(p & 0xffffffffull); }
    }
  }
  if (t == 0) lens[b] = total;
  __syncthreads();
  const int o = t >> 2, sub = t & 3;
  if (o < nrows && o < RPP) {
    int r = rowlist[o];
    int base = rowpos[o];
    int lo = 0, hi = RTOT - 1;
    while (lo < hi) { int mid = (lo + hi + 1) >> 1; if (time_ptr[mid] <= r) lo = mid; else hi = mid - 1; }
    float tv = times[lo];
    float sv[NTS], cv[NTS];
#pragma unroll
    for (int i = 0; i < NTS; ++i) {
      float a = tv * inv_ts[i];
      sv[i] = sinf(a); cv[i] = cosf(a);
    }
    int cnt = 0;
    const int cb = sub * 8;
    for (int vv = 0; vv < cb; ++vv) cnt += (M[r * NV + vv] != 0);
    int pos = base + cnt;
    for (int vv = cb; vv < cb + 8; ++vv) {
      if (M[r * NV + vv] != 0) {
        unsigned int* fp = (unsigned int*)(feats + ((size_t)b * LMAX + pos) * NIN);
#pragma unroll
        for (int i = 0; i < 8; ++i) fp[i] = pack2(f2b(sv[2 * i]), f2b(sv[2 * i + 1]));
#pragma unroll
        for (int i = 0; i < 8; ++i) fp[8 + i] = pack2(f2b(cv[2 * i]), f2b(cv[2 * i + 1]));
        fp[16] = pack2(f2b((float)vv), f2b(X[r * NV + vv]));
#pragma unroll
        for (int i = 17; i < 32; ++i) fp[i] = 0u;
        ++pos;
      }
    }
  }
  // pad fill: [total, LMAX) gets [0 x16 | 1.0 x16 | 0,0 | 0...]
  {
    uint4 z = make_uint4(0u, 0u, 0u, 0u);
    uint4 one; one.x = one.y = one.z = one.w = 0x3F803F80u;
    for (int pos = total + t; pos < LMAX; pos += 256) {
      uint4* fp = (uint4*)(feats + ((size_t)b * LMAX + pos) * NIN);
      fp[0] = z; fp[1] = z; fp[2] = one; fp[3] = one;
      fp[4] = z; fp[5] = z; fp[6] = z; fp[7] = z;
    }
  }
}

// ---------------------------------------------------------------------------
// K2: fused 3-layer MLP via MFMA bf16 16x16x32, fp32 accum + fp32 enc out.
// ---------------------------------------------------------------------------
__global__ __launch_bounds__(256) void k2_mlp(
    const ushort* __restrict__ feats, const ushort* __restrict__ W0p,
    const float* __restrict__ b0, const ushort* __restrict__ W1b,
    const float* __restrict__ b1, const ushort* __restrict__ W2b,
    const float* __restrict__ b2, float* __restrict__ enc)
{
  __shared__ ushort bufA[64 * LDSP];
  __shared__ ushort bufB[64 * LDSP];
  const int tid = threadIdx.x;
  const int wv = tid >> 6, lane = tid & 63;
  const int m16 = lane & 15, quad = lane >> 4;
  const int rowl = wv * 16 + m16;
  const size_t grow = (size_t)blockIdx.x * 64;
  {
    const short8* ar = (const short8*)(feats + (grow + rowl) * NIN);
    short8 a0 = ar[quad];
    short8 a1 = ar[4 + quad];
#pragma unroll
    for (int nt = 0; nt < 8; ++nt) {
      int n = nt * 16 + m16;
      const short8* br = (const short8*)(W0p + n * NIN);
      floatx4 acc = {0.f, 0.f, 0.f, 0.f};
      acc = __builtin_amdgcn_mfma_f32_16x16x32_bf16(a0, br[quad], acc, 0, 0, 0);
      acc = __builtin_amdgcn_mfma_f32_16x16x32_bf16(a1, br[4 + quad], acc, 0, 0, 0);
      float bias = b0[n];
#pragma unroll
      for (int i = 0; i < 4; ++i) {
        float vv = fmaxf(acc[i] + bias, 0.0f);
        bufA[(wv * 16 + quad * 4 + i) * LDSP + n] = f2b(vv);
      }
    }
  }
  __syncthreads();
  {
#pragma unroll
    for (int nt = 0; nt < 8; ++nt) {
      int n = nt * 16 + m16;
      floatx4 acc = {0.f, 0.f, 0.f, 0.f};
#pragma unroll
      for (int ks = 0; ks < 4; ++ks) {
        short8 a = *(const short8*)(bufA + rowl * LDSP + ks * 32 + quad * 8);
        short8 bb = *(const short8*)(W1b + n * HW + ks * 32 + quad * 8);
        acc = __builtin_amdgcn_mfma_f32_16x16x32_bf16(a, bb, acc, 0, 0, 0);
      }
      float bias = b1[n];
#pragma unroll
      for (int i = 0; i < 4; ++i) {
        float vv = fmaxf(acc[i] + bias, 0.0f);
        bufB[(wv * 16 + quad * 4 + i) * LDSP + n] = f2b(vv);
      }
    }
  }
  __syncthreads();
  {
#pragma unroll
    for (int nt = 0; nt < 8; ++nt) {
      int n = nt * 16 + m16;
      floatx4 acc = {0.f, 0.f, 0.f, 0.f};
#pragma unroll
      for (int ks = 0; ks < 4; ++ks) {
        short8 a = *(const short8*)(bufB + rowl * LDSP + ks * 32 + quad * 8);
        short8 bb = *(const short8*)(W2b + n * HW + ks * 32 + quad * 8);
        acc = __builtin_amdgcn_mfma_f32_16x16x32_bf16(a, bb, acc, 0, 0, 0);
      }
      float bias = b2[n];
#pragma unroll
      for (int i = 0; i < 4; ++i) {
        enc[(grow + wv * 16 + quad * 4 + i) * HW + n] = acc[i] + bias;
      }
    }
  }
}

// ---------------------------------------------------------------------------
// K3a: per-patient q and folded r = (Wk_h^T q_h)/sqrt(hd). bk dropped
// (softmax-invariant). 32 blocks.
// ---------------------------------------------------------------------------
__global__ __launch_bounds__(256) void k3_qr(
    const float* __restrict__ enc, const float* __restrict__ Wq,
    const float* __restrict__ bq, const float* __restrict__ Wk,
    float* __restrict__ r_all)
{
  const int b = blockIdx.x;
  const int tid = threadIdx.x;
  __shared__ float encq_s[HW], q_s[HW];
  const float* encb = enc + (size_t)b * LMAX * HW;
  if (tid < HW) encq_s[tid] = encb[(LMAX - 1) * HW + tid];
  __syncthreads();
  if (tid < HW) {
    float acc = bq[tid];
    const float4* wr = (const float4*)(Wq + tid * HW);
#pragma unroll 8
    for (int e4 = 0; e4 < 32; ++e4) {
      float4 w4 = wr[e4];
      acc += w4.x * encq_s[e4 * 4 + 0] + w4.y * encq_s[e4 * 4 + 1] +
             w4.z * encq_s[e4 * 4 + 2] + w4.w * encq_s[e4 * 4 + 3];
    }
    q_s[tid] = acc;
  }
  __syncthreads();
  const float scale = 0.17677669529663687f;
  for (int idx = tid; idx < 512; idx += 256) {
    int h = idx >> 7, e = idx & 127;
    float acc = 0.f;
#pragma unroll 8
    for (int d = 0; d < 32; ++d) acc += Wk[(h * 32 + d) * HW + e] * q_s[h * 32 + d];
    r_all[b * 512 + idx] = acc * scale;
  }
}

// ---------------------------------------------------------------------------
// K3b: chunked logits + local softmax + partial weighted sums.
// Block = (patient, chunk of 63 m). 512 blocks -> 2 blocks/CU.
// ---------------------------------------------------------------------------
__global__ __launch_bounds__(256) void k3_chunk(
    const float* __restrict__ enc, const int* __restrict__ lens,
    const float* __restrict__ r_all, float* __restrict__ partial,
    float2* __restrict__ mxsm)
{
  const int bx = blockIdx.x;
  const int b = bx >> 4, c = bx & 15;
  const int tid = threadIdx.x;
  const int len = lens[b];
  const int start = c * CH;
  int valid = len - start; if (valid > CH) valid = CH;
  if (valid <= 0) {
    if (tid < 4) mxsm[bx * 4 + tid] = make_float2(-1e30f, 0.0f);
    return;
  }
  __shared__ float encs[CH * ELD];
  __shared__ float r_s[4 * RLD];
  __shared__ float lg[4 * 64];
  __shared__ float mx_s[4], sm_s[4];
  const float* encb = enc + ((size_t)b * LMAX + start) * HW;
  // stage enc rows (float4, coalesced)
  for (int i = tid; i < valid * 32; i += 256) {
    int row = i >> 5, e4 = i & 31;
    float4 v = ((const float4*)(encb + row * HW))[e4];
    *(float4*)(&encs[row * ELD + e4 * 4]) = v;
  }
  for (int i = tid; i < 512; i += 256)
    r_s[(i >> 7) * RLD + (i & 127)] = r_all[b * 512 + i];
  __syncthreads();
  // logits: thread -> (m = tid>>2, h = tid&3)
  {
    int m = tid >> 2, h = tid & 3;
    if (m < valid) {
      const float4* ev = (const float4*)(&encs[m * ELD]);
      const float4* rv = (const float4*)(&r_s[h * RLD]);
      float acc = 0.f;
#pragma unroll
      for (int e4 = 0; e4 < 32; ++e4) {
        float4 v = ev[e4], r = rv[e4];
        acc += v.x * r.x + v.y * r.y + v.z * r.z + v.w * r.w;
      }
      lg[h * 64 + m] = acc;
    }
  }
  __syncthreads();
  // local softmax per head: wave wv handles head wv
  {
    const int wv = tid >> 6, lane = tid & 63;
    float v = (lane < valid) ? lg[wv * 64 + lane] : -1e30f;
    float mx = v;
#pragma unroll
    for (int o = 32; o >= 1; o >>= 1) mx = fmaxf(mx, __shfl_xor(mx, o));
    float p = (lane < valid) ? expf(v - mx) : 0.f;
    lg[wv * 64 + lane] = p;
    float sm = p;
#pragma unroll
    for (int o = 32; o >= 1; o >>= 1) sm += __shfl_xor(sm, o);
    if (lane == 0) { mx_s[wv] = mx; sm_s[wv] = sm; }
  }
  __syncthreads();
  // partial weighted sums (unnormalized)
  for (int idx = tid; idx < 512; idx += 256) {
    int h = idx >> 7, e = idx & 127;
    float acc = 0.f;
    for (int m = 0; m < valid; ++m)
      acc += lg[h * 64 + m] * encs[m * ELD + e];
    partial[(size_t)bx * 512 + idx] = acc;
  }
  if (tid < 4) mxsm[bx * 4 + tid] = make_float2(mx_s[tid], sm_s[tid]);
}

// ---------------------------------------------------------------------------
// K4: combine chunks with online-softmax rescaling. 32 blocks.
// ---------------------------------------------------------------------------
__global__ __launch_bounds__(256) void k4_combine(
    const float* __restrict__ partial, const float2* __restrict__ mxsm,
    float* __restrict__ out)
{
  const int b = blockIdx.x;
  const int tid = threadIdx.x;
  __shared__ float f_s[NCH * 4];
  if (tid < 4) {
    int h = tid;
    float2 v[NCH];
    float M = -1e30f;
#pragma unroll
    for (int c = 0; c < NCH; ++c) {
      v[c] = mxsm[(b * NCH + c) * 4 + h];
      if (v[c].y > 0.f) M = fmaxf(M, v[c].x);
    }
    float S = 0.f;
#pragma unroll
    for (int c = 0; c < NCH; ++c)
      if (v[c].y > 0.f) S += v[c].y * expf(v[c].x - M);
    float invS = 1.0f / S;
#pragma unroll
    for (int c = 0; c < NCH; ++c)
      f_s[c * 4 + h] = (v[c].y > 0.f) ? expf(v[c].x - M) * invS : 0.f;
  }
  __syncthreads();
  for (int idx = tid; idx < 512; idx += 256) {
    int h = idx >> 7;
    float acc = 0.f;
#pragma unroll
    for (int c = 0; c < NCH; ++c)
      acc += partial[((size_t)(b * NCH + c)) * 512 + idx] * f_s[c * 4 + h];
    out[b * 512 + idx] = acc;
  }
}

extern "C" void kernel_launch(void* const* d_in, const int* in_sizes, int n_in,
                              void* d_out, int out_size, void* d_ws, size_t ws_size,
                              hipStream_t stream) {
  const float* times = (const float*)d_in[0];
  const int* time_ptr = (const int*)d_in[1];
  const float* X = (const float*)d_in[2];
  const int* M = (const int*)d_in[3];
  const int* obs_idx = (const int*)d_in[4];
  const float* W0 = (const float*)d_in[6];
  const float* b0 = (const float*)d_in[7];
  const float* W1 = (const float*)d_in[8];
  const float* b1 = (const float*)d_in[9];
  const float* W2 = (const float*)d_in[10];
  const float* b2 = (const float*)d_in[11];
  const float* Wq = (const float*)d_in[12];
  const float* bq = (const float*)d_in[13];
  const float* Wk = (const float*)d_in[14];
  // d_in[15] (bk) is softmax-invariant for the scores -> dropped.
  float* out = (float*)d_out;

  char* ws = (char*)d_ws;
  size_t off = 0;
  ushort* feats = (ushort*)(ws + off); off += (size_t)B_PAT * LMAX * NIN * sizeof(ushort); // 4.1 MB
  ushort* W0p = (ushort*)(ws + off); off += (size_t)HW * NIN * sizeof(ushort);
  ushort* W1b = (ushort*)(ws + off); off += (size_t)HW * HW * sizeof(ushort);
  ushort* W2b = (ushort*)(ws + off); off += (size_t)HW * HW * sizeof(ushort);
  off = (off + 255) & ~(size_t)255;
  int* lens = (int*)(ws + off); off += 256;
  float* enc = (float*)(ws + off); off += (size_t)B_PAT * LMAX * HW * sizeof(float); // 16.5 MB
  float* r_all = (float*)(ws + off); off += (size_t)B_PAT * 512 * sizeof(float);     // 64 KB
  float* partial = (float*)(ws + off); off += (size_t)B_PAT * NCH * 512 * sizeof(float); // 1 MB
  float2* mxsm = (float2*)(ws + off); off += (size_t)B_PAT * NCH * 4 * sizeof(float2);   // 16 KB

  k1_features<<<B_PAT + 3, 256, 0, stream>>>(times, time_ptr, X, M, obs_idx,
                                             W0, W1, W2, feats, W0p, W1b, W2b, lens);
  k2_mlp<<<(B_PAT * LMAX) / 64, 256, 0, stream>>>(feats, W0p, b0, W1b, b1, W2b, b2, enc);
  k3_qr<<<B_PAT, 256, 0, stream>>>(enc, Wq, bq, Wk, r_all);
  k3_chunk<<<B_PAT * NCH, 256, 0, stream>>>(enc, lens, r_all, partial, mxsm);
  k4_combine<<<B_PAT, 256, 0, stream>>>(partial, mxsm, out);
}

// Round 5
// 151.883 us; speedup vs baseline: 1.1970x; 1.0381x over previous
//
#include <hip/hip_runtime.h>

#define B_PAT 32
#define RPP 64
#define RTOT 2048
#define NV 32
#define LMAX 1008
#define NTS 16
#define NIN 64   // K-padded from 34
#define HW 128   // MLP width / hidden
#define LDSP 136 // LDS row stride for MLP bufs (pad +8 bf16)
#define NCH 16   // attention m-chunks per patient
#define CH 63    // m per chunk (16*63 = 1008)
#define ELD 132  // enc LDS stride (floats), conflict-free & float4-aligned
#define RLD 136  // r LDS stride (floats)

typedef __attribute__((ext_vector_type(8))) short short8;
typedef __attribute__((ext_vector_type(4))) float floatx4;

__device__ __forceinline__ float b2f(ushort u) {
  union { float f; unsigned int i; } v; v.i = ((unsigned int)u) << 16; return v.f;
}
__device__ __forceinline__ ushort f2b(float f) {
  unsigned int x = __float_as_uint(f);
  unsigned int r = (x + 0x7FFFu + ((x >> 16) & 1u)) >> 16;
  return (ushort)r;
}
__device__ __forceinline__ unsigned int pack2(ushort lo, ushort hi) {
  return (unsigned int)lo | ((unsigned int)hi << 16);
}
__device__ __forceinline__ unsigned long long shfl_up_u64(unsigned long long x, int off) {
  int lo = (int)(x & 0xffffffffull), hi = (int)(x >> 32);
  lo = __shfl_up(lo, off); hi = __shfl_up(hi, off);
  return ((unsigned long long)(unsigned int)hi << 32) | (unsigned long long)(unsigned int)lo;
}

// ---------------------------------------------------------------------------
// K1: nonzero scan -> packed per-patient bf16 features (K padded to 64),
// plus per-patient fp32 enc_q -> q -> folded r (bk dropped: softmax-invariant).
// blocks [0,32): patients. block 32: W0->bf16 K-pad. 33: W1->bf16. 34: W2->bf16.
// ---------------------------------------------------------------------------
__global__ __launch_bounds__(256) void k1_features(
    const float* __restrict__ times, const int* __restrict__ time_ptr,
    const float* __restrict__ X, const int* __restrict__ M,
    const int* __restrict__ obs_idx, const float* __restrict__ W0,
    const float* __restrict__ b0, const float* __restrict__ W1,
    const float* __restrict__ b1, const float* __restrict__ W2,
    const float* __restrict__ b2, const float* __restrict__ Wq,
    const float* __restrict__ bq, const float* __restrict__ Wk,
    ushort* __restrict__ feats, ushort* __restrict__ W0p,
    ushort* __restrict__ W1b, ushort* __restrict__ W2b,
    int* __restrict__ lens, float* __restrict__ r_all)
{
  const int b = blockIdx.x;
  const int t = threadIdx.x;
  if (b == B_PAT) {
    for (int i = t; i < HW * NIN; i += 256) {
      int n = i >> 6, k = i & 63;
      W0p[i] = (k < 34) ? f2b(W0[n * 34 + k]) : (ushort)0;
    }
    return;
  }
  if (b == B_PAT + 1) {
    for (int i = t; i < HW * HW; i += 256) W1b[i] = f2b(W1[i]);
    return;
  }
  if (b == B_PAT + 2) {
    for (int i = t; i < HW * HW; i += 256) W2b[i] = f2b(W2[i]);
    return;
  }
  __shared__ float inv_ts[NTS];
  __shared__ unsigned long long wsum[4];
  __shared__ int rowlist[RPP];
  __shared__ int rowpos[RPP];
  if (t < NTS) {
    float ts = powf(100.0f, (float)t * (1.0f / 15.0f));
    inv_ts[t] = 1.0f / ts;
  }
  const int lane = t & 63, wv = t >> 6;
  unsigned long long acc = 0ull;
  unsigned long long pref[8];
  const int rbase = t * 8;
#pragma unroll
  for (int j = 0; j < 8; ++j) {
    int r = rbase + j;
    int c = 0, pres = 0;
    if (obs_idx[r] == b) {
      pres = 1;
      const int4* mp = (const int4*)(M + r * NV);
#pragma unroll
      for (int q = 0; q < 8; ++q) {
        int4 m4 = mp[q];
        c += (m4.x != 0) + (m4.y != 0) + (m4.z != 0) + (m4.w != 0);
      }
    }
    pref[j] = acc;
    acc += (unsigned long long)(unsigned int)c | ((unsigned long long)pres << 32);
  }
  unsigned long long incl = acc;
  for (int off = 1; off < 64; off <<= 1) {
    unsigned long long v = shfl_up_u64(incl, off);
    if (lane >= off) incl += v;
  }
  if (lane == 63) wsum[wv] = incl;
  __syncthreads();
  unsigned long long wbase = 0ull;
  for (int w = 0; w < wv; ++w) wbase += wsum[w];
  unsigned long long totalall = wsum[0] + wsum[1] + wsum[2] + wsum[3];
  const int total = (int)(totalall & 0xffffffffull);
  const int nrows = (int)(totalall >> 32);
  unsigned long long myexcl = wbase + incl - acc;
#pragma unroll
  for (int j = 0; j < 8; ++j) {
    int r = rbase + j;
    if (obs_idx[r] == b) {
      unsigned long long p = myexcl + pref[j];
      int ord = (int)(p >> 32);
      if (ord < RPP) { rowlist[ord] = r; rowpos[ord] = (int)(p & 0xffffffffull); }
    }
  }
  if (t == 0) lens[b] = total;
  __syncthreads();
  const int o = t >> 2, sub = t & 3;
  if (o < nrows && o < RPP) {
    int r = rowlist[o];
    int base = rowpos[o];
    int lo = 0, hi = RTOT - 1;
    while (lo < hi) { int mid = (lo + hi + 1) >> 1; if (time_ptr[mid] <= r) lo = mid; else hi = mid - 1; }
    float tv = times[lo];
    float sv[NTS], cv[NTS];
#pragma unroll
    for (int i = 0; i < NTS; ++i) {
      float a = tv * inv_ts[i];
      sv[i] = sinf(a); cv[i] = cosf(a);
    }
    int cnt = 0;
    const int cb = sub * 8;
    for (int vv = 0; vv < cb; ++vv) cnt += (M[r * NV + vv] != 0);
    int pos = base + cnt;
    for (int vv = cb; vv < cb + 8; ++vv) {
      if (M[r * NV + vv] != 0) {
        unsigned int* fp = (unsigned int*)(feats + ((size_t)b * LMAX + pos) * NIN);
#pragma unroll
        for (int i = 0; i < 8; ++i) fp[i] = pack2(f2b(sv[2 * i]), f2b(sv[2 * i + 1]));
#pragma unroll
        for (int i = 0; i < 8; ++i) fp[8 + i] = pack2(f2b(cv[2 * i]), f2b(cv[2 * i + 1]));
        fp[16] = pack2(f2b((float)vv), f2b(X[r * NV + vv]));
#pragma unroll
        for (int i = 17; i < 32; ++i) fp[i] = 0u;
        ++pos;
      }
    }
  }
  // pad fill: [total, LMAX) gets [0 x16 | 1.0 x16 | 0,0 | 0...]
  {
    uint4 z = make_uint4(0u, 0u, 0u, 0u);
    uint4 one; one.x = one.y = one.z = one.w = 0x3F803F80u;
    for (int pos = total + t; pos < LMAX; pos += 256) {
      uint4* fp = (uint4*)(feats + ((size_t)b * LMAX + pos) * NIN);
      fp[0] = z; fp[1] = z; fp[2] = one; fp[3] = one;
      fp[4] = z; fp[5] = z; fp[6] = z; fp[7] = z;
    }
  }
  // ---- enc_q (fp32 3-GEMV on feat row 1007) -> q -> r_all ----
  __syncthreads();   // feats row 1007 visible to block
  __shared__ float x_s[64];
  __shared__ float h0_s[HW], h1_s[HW], eq_s[HW], q_s[HW];
  __shared__ float part[256];
  if (t < 64) x_s[t] = b2f(feats[((size_t)b * LMAX + (LMAX - 1)) * NIN + t]);
  __syncthreads();
  if (t < HW) {
    float a2 = b0[t];
#pragma unroll 2
    for (int k = 0; k < 34; ++k) a2 += W0[t * 34 + k] * x_s[k];
    h0_s[t] = fmaxf(a2, 0.0f);
  }
  __syncthreads();
  {
    int oo = t & 127, hf = t >> 7;
    float a2 = 0.f;
    const float* wr = W1 + oo * HW + hf * 64;
#pragma unroll 8
    for (int k = 0; k < 64; ++k) a2 += wr[k] * h0_s[hf * 64 + k];
    part[t] = a2;
  }
  __syncthreads();
  if (t < HW) h1_s[t] = fmaxf(part[t] + part[t + 128] + b1[t], 0.0f);
  __syncthreads();
  {
    int oo = t & 127, hf = t >> 7;
    float a2 = 0.f;
    const float* wr = W2 + oo * HW + hf * 64;
#pragma unroll 8
    for (int k = 0; k < 64; ++k) a2 += wr[k] * h1_s[hf * 64 + k];
    part[t] = a2;
  }
  __syncthreads();
  if (t < HW) eq_s[t] = part[t] + part[t + 128] + b2[t];
  __syncthreads();
  {
    int oo = t & 127, hf = t >> 7;
    float a2 = 0.f;
    const float* wr = Wq + oo * HW + hf * 64;
#pragma unroll 8
    for (int k = 0; k < 64; ++k) a2 += wr[k] * eq_s[hf * 64 + k];
    part[t] = a2;
  }
  __syncthreads();
  if (t < HW) q_s[t] = part[t] + part[t + 128] + bq[t];
  __syncthreads();
  const float scale = 0.17677669529663687f;
  for (int idx = t; idx < 512; idx += 256) {
    int h = idx >> 7, e = idx & 127;
    float a2 = 0.f;
#pragma unroll 8
    for (int d = 0; d < 32; ++d) a2 += Wk[(h * 32 + d) * HW + e] * q_s[h * 32 + d];
    r_all[b * 512 + idx] = a2 * scale;
  }
}

// ---------------------------------------------------------------------------
// K2: fused MLP (MFMA bf16, fp32 accum) + chunked attention partials.
// Block = (patient, chunk of 63 m). 512 blocks -> 2 blocks/CU. enc stays in LDS.
// ---------------------------------------------------------------------------
__global__ __launch_bounds__(256) void k2_fused(
    const ushort* __restrict__ feats, const ushort* __restrict__ W0p,
    const float* __restrict__ b0, const ushort* __restrict__ W1b,
    const float* __restrict__ b1, const ushort* __restrict__ W2b,
    const float* __restrict__ b2, const int* __restrict__ lens,
    const float* __restrict__ r_all, float* __restrict__ partial,
    float2* __restrict__ mxsm)
{
  const int bx = blockIdx.x;
  const int b = bx >> 4, c = bx & 15;
  const int tid = threadIdx.x;
  const int len = lens[b];
  const int start = c * CH;
  int valid = len - start; if (valid > CH) valid = CH;
  if (valid <= 0) {
    if (tid < 4) mxsm[bx * 4 + tid] = make_float2(-1e30f, 0.0f);
    for (int i = tid; i < 512; i += 256) partial[(size_t)bx * 512 + i] = 0.f;
    return;
  }
  __shared__ ushort bufA[64 * LDSP];
  __shared__ ushort bufB[64 * LDSP];
  __shared__ float encs[CH * ELD];
  __shared__ float r_s[4 * RLD];
  __shared__ float lg[4 * 64];
  __shared__ float mx_s[4], sm_s[4];
  const int wv = tid >> 6, lane = tid & 63;
  const int m16 = lane & 15, quad = lane >> 4;
  const int rowl = wv * 16 + m16;
  const size_t fbase = (size_t)b * LMAX + start;
  // r for this patient
  for (int i = tid; i < 512; i += 256)
    r_s[(i >> 7) * RLD + (i & 127)] = r_all[b * 512 + i];
  // ---- layer 0: feats[.,64] @ W0p^T (K=64); tile row 63 = dup of 62
  {
    const int arow = (rowl < CH) ? rowl : (CH - 1);
    const short8* ar = (const short8*)(feats + (fbase + arow) * NIN);
    short8 a0 = ar[quad];
    short8 a1 = ar[4 + quad];
#pragma unroll
    for (int nt = 0; nt < 8; ++nt) {
      int n = nt * 16 + m16;
      const short8* br = (const short8*)(W0p + n * NIN);
      floatx4 acc2 = {0.f, 0.f, 0.f, 0.f};
      acc2 = __builtin_amdgcn_mfma_f32_16x16x32_bf16(a0, br[quad], acc2, 0, 0, 0);
      acc2 = __builtin_amdgcn_mfma_f32_16x16x32_bf16(a1, br[4 + quad], acc2, 0, 0, 0);
      float bias = b0[n];
#pragma unroll
      for (int i = 0; i < 4; ++i) {
        float vv = fmaxf(acc2[i] + bias, 0.0f);
        bufA[(wv * 16 + quad * 4 + i) * LDSP + n] = f2b(vv);
      }
    }
  }
  __syncthreads();
  // ---- layer 1 (K=128)
  {
#pragma unroll
    for (int nt = 0; nt < 8; ++nt) {
      int n = nt * 16 + m16;
      floatx4 acc2 = {0.f, 0.f, 0.f, 0.f};
#pragma unroll
      for (int ks = 0; ks < 4; ++ks) {
        short8 a = *(const short8*)(bufA + rowl * LDSP + ks * 32 + quad * 8);
        short8 bb = *(const short8*)(W1b + n * HW + ks * 32 + quad * 8);
        acc2 = __builtin_amdgcn_mfma_f32_16x16x32_bf16(a, bb, acc2, 0, 0, 0);
      }
      float bias = b1[n];
#pragma unroll
      for (int i = 0; i < 4; ++i) {
        float vv = fmaxf(acc2[i] + bias, 0.0f);
        bufB[(wv * 16 + quad * 4 + i) * LDSP + n] = f2b(vv);
      }
    }
  }
  __syncthreads();
  // ---- layer 2 (K=128) -> encs (fp32, LDS), rows < valid only needed
  {
#pragma unroll
    for (int nt = 0; nt < 8; ++nt) {
      int n = nt * 16 + m16;
      floatx4 acc2 = {0.f, 0.f, 0.f, 0.f};
#pragma unroll
      for (int ks = 0; ks < 4; ++ks) {
        short8 a = *(const short8*)(bufB + rowl * LDSP + ks * 32 + quad * 8);
        short8 bb = *(const short8*)(W2b + n * HW + ks * 32 + quad * 8);
        acc2 = __builtin_amdgcn_mfma_f32_16x16x32_bf16(a, bb, acc2, 0, 0, 0);
      }
      float bias = b2[n];
#pragma unroll
      for (int i = 0; i < 4; ++i) {
        int orow = wv * 16 + quad * 4 + i;
        if (orow < CH) encs[orow * ELD + n] = acc2[i] + bias;
      }
    }
  }
  __syncthreads();
  // ---- logits: thread -> (m = tid>>2, h = tid&3)
  {
    int m = tid >> 2, h = tid & 3;
    if (m < valid) {
      const float4* ev = (const float4*)(&encs[m * ELD]);
      const float4* rv = (const float4*)(&r_s[h * RLD]);
      float acc2 = 0.f;
#pragma unroll
      for (int e4 = 0; e4 < 32; ++e4) {
        float4 v = ev[e4], r = rv[e4];
        acc2 += v.x * r.x + v.y * r.y + v.z * r.z + v.w * r.w;
      }
      lg[h * 64 + m] = acc2;
    }
  }
  __syncthreads();
  // ---- local softmax per head (wave wv = head wv)
  {
    float v = (lane < valid) ? lg[wv * 64 + lane] : -1e30f;
    float mx = v;
#pragma unroll
    for (int o = 32; o >= 1; o >>= 1) mx = fmaxf(mx, __shfl_xor(mx, o));
    float p = (lane < valid) ? expf(v - mx) : 0.f;
    lg[wv * 64 + lane] = p;
    float sm = p;
#pragma unroll
    for (int o = 32; o >= 1; o >>= 1) sm += __shfl_xor(sm, o);
    if (lane == 0) { mx_s[wv] = mx; sm_s[wv] = sm; }
  }
  __syncthreads();
  // ---- partial weighted sums (unnormalized)
  for (int idx = tid; idx < 512; idx += 256) {
    int h = idx >> 7, e = idx & 127;
    float acc2 = 0.f;
    for (int m = 0; m < valid; ++m)
      acc2 += lg[h * 64 + m] * encs[m * ELD + e];
    partial[(size_t)bx * 512 + idx] = acc2;
  }
  if (tid < 4) mxsm[bx * 4 + tid] = make_float2(mx_s[tid], sm_s[tid]);
}

// ---------------------------------------------------------------------------
// K4: combine chunks with online-softmax rescaling. 32 blocks.
// ---------------------------------------------------------------------------
__global__ __launch_bounds__(256) void k4_combine(
    const float* __restrict__ partial, const float2* __restrict__ mxsm,
    float* __restrict__ out)
{
  const int b = blockIdx.x;
  const int tid = threadIdx.x;
  __shared__ float f_s[NCH * 4];
  if (tid < 4) {
    int h = tid;
    float2 v[NCH];
    float M = -1e30f;
#pragma unroll
    for (int c = 0; c < NCH; ++c) {
      v[c] = mxsm[(b * NCH + c) * 4 + h];
      if (v[c].y > 0.f) M = fmaxf(M, v[c].x);
    }
    float S = 0.f;
#pragma unroll
    for (int c = 0; c < NCH; ++c)
      if (v[c].y > 0.f) S += v[c].y * expf(v[c].x - M);
    float invS = 1.0f / S;
#pragma unroll
    for (int c = 0; c < NCH; ++c)
      f_s[c * 4 + h] = (v[c].y > 0.f) ? expf(v[c].x - M) * invS : 0.f;
  }
  __syncthreads();
  for (int idx = tid; idx < 512; idx += 256) {
    int h = idx >> 7;
    float acc = 0.f;
#pragma unroll
    for (int c = 0; c < NCH; ++c)
      acc += partial[((size_t)(b * NCH + c)) * 512 + idx] * f_s[c * 4 + h];
    out[b * 512 + idx] = acc;
  }
}

extern "C" void kernel_launch(void* const* d_in, const int* in_sizes, int n_in,
                              void* d_out, int out_size, void* d_ws, size_t ws_size,
                              hipStream_t stream) {
  const float* times = (const float*)d_in[0];
  const int* time_ptr = (const int*)d_in[1];
  const float* X = (const float*)d_in[2];
  const int* M = (const int*)d_in[3];
  const int* obs_idx = (const int*)d_in[4];
  const float* W0 = (const float*)d_in[6];
  const float* b0 = (const float*)d_in[7];
  const float* W1 = (const float*)d_in[8];
  const float* b1 = (const float*)d_in[9];
  const float* W2 = (const float*)d_in[10];
  const float* b2 = (const float*)d_in[11];
  const float* Wq = (const float*)d_in[12];
  const float* bq = (const float*)d_in[13];
  const float* Wk = (const float*)d_in[14];
  // d_in[15] (bk) is softmax-invariant for the scores -> dropped.
  float* out = (float*)d_out;

  char* ws = (char*)d_ws;
  size_t off = 0;
  ushort* feats = (ushort*)(ws + off); off += (size_t)B_PAT * LMAX * NIN * sizeof(ushort); // 4.1 MB
  ushort* W0p = (ushort*)(ws + off); off += (size_t)HW * NIN * sizeof(ushort);
  ushort* W1b = (ushort*)(ws + off); off += (size_t)HW * HW * sizeof(ushort);
  ushort* W2b = (ushort*)(ws + off); off += (size_t)HW * HW * sizeof(ushort);
  off = (off + 255) & ~(size_t)255;
  int* lens = (int*)(ws + off); off += 256;
  float* r_all = (float*)(ws + off); off += (size_t)B_PAT * 512 * sizeof(float);         // 64 KB
  float* partial = (float*)(ws + off); off += (size_t)B_PAT * NCH * 512 * sizeof(float); // 1 MB
  float2* mxsm = (float2*)(ws + off); off += (size_t)B_PAT * NCH * 4 * sizeof(float2);   // 16 KB

  k1_features<<<B_PAT + 3, 256, 0, stream>>>(times, time_ptr, X, M, obs_idx,
                                             W0, b0, W1, b1, W2, b2, Wq, bq, Wk,
                                             feats, W0p, W1b, W2b, lens, r_all);
  k2_fused<<<B_PAT * NCH, 256, 0, stream>>>(feats, W0p, b0, W1b, b1, W2b, b2,
                                            lens, r_all, partial, mxsm);
  k4_combine<<<B_PAT, 256, 0, stream>>>(partial, mxsm, out);
}

// Round 6
// 150.837 us; speedup vs baseline: 1.2053x; 1.0069x over previous
//
#include <hip/hip_runtime.h>

#define B_PAT 32
#define RPP 64
#define RTOT 2048
#define NV 32
#define LMAX 1008
#define NTS 16
#define NIN 64   // K-padded from 34
#define HW 128   // MLP width / hidden
#define LDSP 136 // LDS row stride for MLP bufs (pad +8 bf16)
#define NCH 16   // attention m-chunks per patient
#define CH 63    // m per chunk (16*63 = 1008)
#define ELD 132  // enc LDS stride (floats), conflict-free & float4-aligned
#define RLD 136  // r LDS stride (floats)

typedef __attribute__((ext_vector_type(8))) short short8;
typedef __attribute__((ext_vector_type(4))) float floatx4;

__device__ __forceinline__ float b2f(ushort u) {
  union { float f; unsigned int i; } v; v.i = ((unsigned int)u) << 16; return v.f;
}
__device__ __forceinline__ ushort f2b(float f) {
  unsigned int x = __float_as_uint(f);
  unsigned int r = (x + 0x7FFFu + ((x >> 16) & 1u)) >> 16;
  return (ushort)r;
}
__device__ __forceinline__ unsigned int pack2(ushort lo, ushort hi) {
  return (unsigned int)lo | ((unsigned int)hi << 16);
}
__device__ __forceinline__ unsigned long long shfl_up_u64(unsigned long long x, int off) {
  int lo = (int)(x & 0xffffffffull), hi = (int)(x >> 32);
  lo = __shfl_up(lo, off); hi = __shfl_up(hi, off);
  return ((unsigned long long)(unsigned int)hi << 32) | (unsigned long long)(unsigned int)lo;
}

// ---------------------------------------------------------------------------
// K1: nonzero scan -> per-patient bf16 features staged in LDS (126 KB), then
// one coalesced block copy to global; plus fp32 enc_q -> q -> folded r.
// blocks [0,32): patients. block 32: W0->bf16 K-pad. 33: W1->bf16. 34: W2->bf16.
// ---------------------------------------------------------------------------
__global__ __launch_bounds__(256) void k1_features(
    const float* __restrict__ times, const int* __restrict__ time_ptr,
    const float* __restrict__ X, const int* __restrict__ M,
    const int* __restrict__ obs_idx, const float* __restrict__ W0,
    const float* __restrict__ b0, const float* __restrict__ W1,
    const float* __restrict__ b1, const float* __restrict__ W2,
    const float* __restrict__ b2, const float* __restrict__ Wq,
    const float* __restrict__ bq, const float* __restrict__ Wk,
    ushort* __restrict__ feats, ushort* __restrict__ W0p,
    ushort* __restrict__ W1b, ushort* __restrict__ W2b,
    int* __restrict__ lens, float* __restrict__ r_all)
{
  const int b = blockIdx.x;
  const int t = threadIdx.x;
  if (b == B_PAT) {
    for (int i = t; i < HW * NIN; i += 256) {
      int n = i >> 6, k = i & 63;
      W0p[i] = (k < 34) ? f2b(W0[n * 34 + k]) : (ushort)0;
    }
    return;
  }
  if (b == B_PAT + 1) {
    for (int i = t; i < HW * HW; i += 256) W1b[i] = f2b(W1[i]);
    return;
  }
  if (b == B_PAT + 2) {
    for (int i = t; i < HW * HW; i += 256) W2b[i] = f2b(W2[i]);
    return;
  }
  __shared__ ushort stage[LMAX * NIN];   // 126 KB feature staging
  __shared__ float inv_ts[NTS];
  __shared__ unsigned long long wsum[4];
  __shared__ int rowlist[RPP];
  __shared__ int rowpos[RPP];
  if (t < NTS) {
    float ts = powf(100.0f, (float)t * (1.0f / 15.0f));
    inv_ts[t] = 1.0f / ts;
  }
  const int lane = t & 63, wv = t >> 6;
  unsigned long long acc = 0ull;
  unsigned long long pref[8];
  const int rbase = t * 8;
#pragma unroll
  for (int j = 0; j < 8; ++j) {
    int r = rbase + j;
    int c = 0, pres = 0;
    if (obs_idx[r] == b) {
      pres = 1;
      const int4* mp = (const int4*)(M + r * NV);
#pragma unroll
      for (int q = 0; q < 8; ++q) {
        int4 m4 = mp[q];
        c += (m4.x != 0) + (m4.y != 0) + (m4.z != 0) + (m4.w != 0);
      }
    }
    pref[j] = acc;
    acc += (unsigned long long)(unsigned int)c | ((unsigned long long)pres << 32);
  }
  unsigned long long incl = acc;
  for (int off = 1; off < 64; off <<= 1) {
    unsigned long long v = shfl_up_u64(incl, off);
    if (lane >= off) incl += v;
  }
  if (lane == 63) wsum[wv] = incl;
  __syncthreads();
  unsigned long long wbase = 0ull;
  for (int w = 0; w < wv; ++w) wbase += wsum[w];
  unsigned long long totalall = wsum[0] + wsum[1] + wsum[2] + wsum[3];
  const int total = (int)(totalall & 0xffffffffull);
  const int nrows = (int)(totalall >> 32);
  unsigned long long myexcl = wbase + incl - acc;
#pragma unroll
  for (int j = 0; j < 8; ++j) {
    int r = rbase + j;
    if (obs_idx[r] == b) {
      unsigned long long p = myexcl + pref[j];
      int ord = (int)(p >> 32);
      if (ord < RPP) { rowlist[ord] = r; rowpos[ord] = (int)(p & 0xffffffffull); }
    }
  }
  if (t == 0) lens[b] = total;
  __syncthreads();
  // ---- scatter features into LDS stage: 4 threads per patient-row
  const int o = t >> 2, sub = t & 3;
  if (o < nrows && o < RPP) {
    int r = rowlist[o];
    int base = rowpos[o];
    int lo = 0, hi = RTOT - 1;
    while (lo < hi) { int mid = (lo + hi + 1) >> 1; if (time_ptr[mid] <= r) lo = mid; else hi = mid - 1; }
    float tv = times[lo];
    float sv[NTS], cv[NTS];
#pragma unroll
    for (int i = 0; i < NTS; ++i) {
      float a = tv * inv_ts[i];
      sv[i] = sinf(a); cv[i] = cosf(a);
    }
    int cnt = 0;
    const int cb = sub * 8;
    for (int vv = 0; vv < cb; ++vv) cnt += (M[r * NV + vv] != 0);
    int pos = base + cnt;
    for (int vv = cb; vv < cb + 8; ++vv) {
      if (M[r * NV + vv] != 0) {
        unsigned int* fp = (unsigned int*)(stage + pos * NIN);
#pragma unroll
        for (int i = 0; i < 8; ++i) fp[i] = pack2(f2b(sv[2 * i]), f2b(sv[2 * i + 1]));
#pragma unroll
        for (int i = 0; i < 8; ++i) fp[8 + i] = pack2(f2b(cv[2 * i]), f2b(cv[2 * i + 1]));
        fp[16] = pack2(f2b((float)vv), f2b(X[r * NV + vv]));
#pragma unroll
        for (int i = 17; i < 32; ++i) fp[i] = 0u;
        ++pos;
      }
    }
  }
  // pad rows [total, LMAX): [0 x16 | 1.0 x16 | 0,0 | 0...]
  {
    uint4 z = make_uint4(0u, 0u, 0u, 0u);
    uint4 one; one.x = one.y = one.z = one.w = 0x3F803F80u;
    for (int pos = total + t; pos < LMAX; pos += 256) {
      uint4* fp = (uint4*)(stage + pos * NIN);
      fp[0] = z; fp[1] = z; fp[2] = one; fp[3] = one;
      fp[4] = z; fp[5] = z; fp[6] = z; fp[7] = z;
    }
  }
  __syncthreads();
  // ---- coalesced copy LDS stage -> global feats (uint4 streams)
  {
    const uint4* src = (const uint4*)stage;
    uint4* dst = (uint4*)(feats + (size_t)b * LMAX * NIN);
    for (int idx = t; idx < LMAX * 8; idx += 256) dst[idx] = src[idx];
  }
  // ---- enc_q (fp32 3-GEMV on stage row 1007) -> q -> r_all ----
  __shared__ float x_s[64];
  __shared__ float h0_s[HW], h1_s[HW], eq_s[HW], q_s[HW];
  __shared__ float part[256];
  if (t < 64) x_s[t] = b2f(stage[(LMAX - 1) * NIN + t]);
  __syncthreads();
  if (t < HW) {
    float a2 = b0[t];
#pragma unroll 2
    for (int k = 0; k < 34; ++k) a2 += W0[t * 34 + k] * x_s[k];
    h0_s[t] = fmaxf(a2, 0.0f);
  }
  __syncthreads();
  {
    int oo = t & 127, hf = t >> 7;
    float a2 = 0.f;
    const float* wr = W1 + oo * HW + hf * 64;
#pragma unroll 8
    for (int k = 0; k < 64; ++k) a2 += wr[k] * h0_s[hf * 64 + k];
    part[t] = a2;
  }
  __syncthreads();
  if (t < HW) h1_s[t] = fmaxf(part[t] + part[t + 128] + b1[t], 0.0f);
  __syncthreads();
  {
    int oo = t & 127, hf = t >> 7;
    float a2 = 0.f;
    const float* wr = W2 + oo * HW + hf * 64;
#pragma unroll 8
    for (int k = 0; k < 64; ++k) a2 += wr[k] * h1_s[hf * 64 + k];
    part[t] = a2;
  }
  __syncthreads();
  if (t < HW) eq_s[t] = part[t] + part[t + 128] + b2[t];
  __syncthreads();
  {
    int oo = t & 127, hf = t >> 7;
    float a2 = 0.f;
    const float* wr = Wq + oo * HW + hf * 64;
#pragma unroll 8
    for (int k = 0; k < 64; ++k) a2 += wr[k] * eq_s[hf * 64 + k];
    part[t] = a2;
  }
  __syncthreads();
  if (t < HW) q_s[t] = part[t] + part[t + 128] + bq[t];
  __syncthreads();
  const float scale = 0.17677669529663687f;
  for (int idx = t; idx < 512; idx += 256) {
    int h = idx >> 7, e = idx & 127;
    float a2 = 0.f;
#pragma unroll 8
    for (int d = 0; d < 32; ++d) a2 += Wk[(h * 32 + d) * HW + e] * q_s[h * 32 + d];
    r_all[b * 512 + idx] = a2 * scale;
  }
}

// ---------------------------------------------------------------------------
// K2: fused MLP (MFMA bf16, fp32 accum) + chunked attention partials.
// Block = (patient, chunk of 63 m). 512 blocks -> 2 blocks/CU. enc stays in LDS.
// ---------------------------------------------------------------------------
__global__ __launch_bounds__(256) void k2_fused(
    const ushort* __restrict__ feats, const ushort* __restrict__ W0p,
    const float* __restrict__ b0, const ushort* __restrict__ W1b,
    const float* __restrict__ b1, const ushort* __restrict__ W2b,
    const float* __restrict__ b2, const int* __restrict__ lens,
    const float* __restrict__ r_all, float* __restrict__ partial,
    float2* __restrict__ mxsm)
{
  const int bx = blockIdx.x;
  const int b = bx >> 4, c = bx & 15;
  const int tid = threadIdx.x;
  const int len = lens[b];
  const int start = c * CH;
  int valid = len - start; if (valid > CH) valid = CH;
  if (valid <= 0) {
    if (tid < 4) mxsm[bx * 4 + tid] = make_float2(-1e30f, 0.0f);
    for (int i = tid; i < 512; i += 256) partial[(size_t)bx * 512 + i] = 0.f;
    return;
  }
  __shared__ ushort bufA[64 * LDSP];
  __shared__ ushort bufB[64 * LDSP];
  __shared__ float encs[CH * ELD];
  __shared__ float r_s[4 * RLD];
  __shared__ float lg[4 * 64];
  __shared__ float mx_s[4], sm_s[4];
  const int wv = tid >> 6, lane = tid & 63;
  const int m16 = lane & 15, quad = lane >> 4;
  const int rowl = wv * 16 + m16;
  const size_t fbase = (size_t)b * LMAX + start;
  for (int i = tid; i < 512; i += 256)
    r_s[(i >> 7) * RLD + (i & 127)] = r_all[b * 512 + i];
  // ---- layer 0: feats[.,64] @ W0p^T (K=64); tile row 63 = dup of 62
  {
    const int arow = (rowl < CH) ? rowl : (CH - 1);
    const short8* ar = (const short8*)(feats + (fbase + arow) * NIN);
    short8 a0 = ar[quad];
    short8 a1 = ar[4 + quad];
#pragma unroll
    for (int nt = 0; nt < 8; ++nt) {
      int n = nt * 16 + m16;
      const short8* br = (const short8*)(W0p + n * NIN);
      floatx4 acc2 = {0.f, 0.f, 0.f, 0.f};
      acc2 = __builtin_amdgcn_mfma_f32_16x16x32_bf16(a0, br[quad], acc2, 0, 0, 0);
      acc2 = __builtin_amdgcn_mfma_f32_16x16x32_bf16(a1, br[4 + quad], acc2, 0, 0, 0);
      float bias = b0[n];
#pragma unroll
      for (int i = 0; i < 4; ++i) {
        float vv = fmaxf(acc2[i] + bias, 0.0f);
        bufA[(wv * 16 + quad * 4 + i) * LDSP + n] = f2b(vv);
      }
    }
  }
  __syncthreads();
  // ---- layer 1 (K=128)
  {
#pragma unroll
    for (int nt = 0; nt < 8; ++nt) {
      int n = nt * 16 + m16;
      floatx4 acc2 = {0.f, 0.f, 0.f, 0.f};
#pragma unroll
      for (int ks = 0; ks < 4; ++ks) {
        short8 a = *(const short8*)(bufA + rowl * LDSP + ks * 32 + quad * 8);
        short8 bb = *(const short8*)(W1b + n * HW + ks * 32 + quad * 8);
        acc2 = __builtin_amdgcn_mfma_f32_16x16x32_bf16(a, bb, acc2, 0, 0, 0);
      }
      float bias = b1[n];
#pragma unroll
      for (int i = 0; i < 4; ++i) {
        float vv = fmaxf(acc2[i] + bias, 0.0f);
        bufB[(wv * 16 + quad * 4 + i) * LDSP + n] = f2b(vv);
      }
    }
  }
  __syncthreads();
  // ---- layer 2 (K=128) -> encs (fp32, LDS)
  {
#pragma unroll
    for (int nt = 0; nt < 8; ++nt) {
      int n = nt * 16 + m16;
      floatx4 acc2 = {0.f, 0.f, 0.f, 0.f};
#pragma unroll
      for (int ks = 0; ks < 4; ++ks) {
        short8 a = *(const short8*)(bufB + rowl * LDSP + ks * 32 + quad * 8);
        short8 bb = *(const short8*)(W2b + n * HW + ks * 32 + quad * 8);
        acc2 = __builtin_amdgcn_mfma_f32_16x16x32_bf16(a, bb, acc2, 0, 0, 0);
      }
      float bias = b2[n];
#pragma unroll
      for (int i = 0; i < 4; ++i) {
        int orow = wv * 16 + quad * 4 + i;
        if (orow < CH) encs[orow * ELD + n] = acc2[i] + bias;
      }
    }
  }
  __syncthreads();
  // ---- logits: thread -> (m = tid>>2, h = tid&3)
  {
    int m = tid >> 2, h = tid & 3;
    if (m < valid) {
      const float4* ev = (const float4*)(&encs[m * ELD]);
      const float4* rv = (const float4*)(&r_s[h * RLD]);
      float acc2 = 0.f;
#pragma unroll
      for (int e4 = 0; e4 < 32; ++e4) {
        float4 v = ev[e4], r = rv[e4];
        acc2 += v.x * r.x + v.y * r.y + v.z * r.z + v.w * r.w;
      }
      lg[h * 64 + m] = acc2;
    }
  }
  __syncthreads();
  // ---- local softmax per head (wave wv = head wv)
  {
    float v = (lane < valid) ? lg[wv * 64 + lane] : -1e30f;
    float mx = v;
#pragma unroll
    for (int o = 32; o >= 1; o >>= 1) mx = fmaxf(mx, __shfl_xor(mx, o));
    float p = (lane < valid) ? expf(v - mx) : 0.f;
    lg[wv * 64 + lane] = p;
    float sm = p;
#pragma unroll
    for (int o = 32; o >= 1; o >>= 1) sm += __shfl_xor(sm, o);
    if (lane == 0) { mx_s[wv] = mx; sm_s[wv] = sm; }
  }
  __syncthreads();
  // ---- partial weighted sums (unnormalized)
  for (int idx = tid; idx < 512; idx += 256) {
    int h = idx >> 7, e = idx & 127;
    float acc2 = 0.f;
    for (int m = 0; m < valid; ++m)
      acc2 += lg[h * 64 + m] * encs[m * ELD + e];
    partial[(size_t)bx * 512 + idx] = acc2;
  }
  if (tid < 4) mxsm[bx * 4 + tid] = make_float2(mx_s[tid], sm_s[tid]);
}

// ---------------------------------------------------------------------------
// K4: combine chunks with online-softmax rescaling. 32 blocks.
// ---------------------------------------------------------------------------
__global__ __launch_bounds__(256) void k4_combine(
    const float* __restrict__ partial, const float2* __restrict__ mxsm,
    float* __restrict__ out)
{
  const int b = blockIdx.x;
  const int tid = threadIdx.x;
  __shared__ float f_s[NCH * 4];
  if (tid < 4) {
    int h = tid;
    float2 v[NCH];
    float M = -1e30f;
#pragma unroll
    for (int c = 0; c < NCH; ++c) {
      v[c] = mxsm[(b * NCH + c) * 4 + h];
      if (v[c].y > 0.f) M = fmaxf(M, v[c].x);
    }
    float S = 0.f;
#pragma unroll
    for (int c = 0; c < NCH; ++c)
      if (v[c].y > 0.f) S += v[c].y * expf(v[c].x - M);
    float invS = 1.0f / S;
#pragma unroll
    for (int c = 0; c < NCH; ++c)
      f_s[c * 4 + h] = (v[c].y > 0.f) ? expf(v[c].x - M) * invS : 0.f;
  }
  __syncthreads();
  for (int idx = tid; idx < 512; idx += 256) {
    int h = idx >> 7;
    float acc = 0.f;
#pragma unroll
    for (int c = 0; c < NCH; ++c)
      acc += partial[((size_t)(b * NCH + c)) * 512 + idx] * f_s[c * 4 + h];
    out[b * 512 + idx] = acc;
  }
}

extern "C" void kernel_launch(void* const* d_in, const int* in_sizes, int n_in,
                              void* d_out, int out_size, void* d_ws, size_t ws_size,
                              hipStream_t stream) {
  const float* times = (const float*)d_in[0];
  const int* time_ptr = (const int*)d_in[1];
  const float* X = (const float*)d_in[2];
  const int* M = (const int*)d_in[3];
  const int* obs_idx = (const int*)d_in[4];
  const float* W0 = (const float*)d_in[6];
  const float* b0 = (const float*)d_in[7];
  const float* W1 = (const float*)d_in[8];
  const float* b1 = (const float*)d_in[9];
  const float* W2 = (const float*)d_in[10];
  const float* b2 = (const float*)d_in[11];
  const float* Wq = (const float*)d_in[12];
  const float* bq = (const float*)d_in[13];
  const float* Wk = (const float*)d_in[14];
  // d_in[15] (bk) is softmax-invariant for the scores -> dropped.
  float* out = (float*)d_out;

  char* ws = (char*)d_ws;
  size_t off = 0;
  ushort* feats = (ushort*)(ws + off); off += (size_t)B_PAT * LMAX * NIN * sizeof(ushort); // 4.1 MB
  ushort* W0p = (ushort*)(ws + off); off += (size_t)HW * NIN * sizeof(ushort);
  ushort* W1b = (ushort*)(ws + off); off += (size_t)HW * HW * sizeof(ushort);
  ushort* W2b = (ushort*)(ws + off); off += (size_t)HW * HW * sizeof(ushort);
  off = (off + 255) & ~(size_t)255;
  int* lens = (int*)(ws + off); off += 256;
  float* r_all = (float*)(ws + off); off += (size_t)B_PAT * 512 * sizeof(float);         // 64 KB
  float* partial = (float*)(ws + off); off += (size_t)B_PAT * NCH * 512 * sizeof(float); // 1 MB
  float2* mxsm = (float2*)(ws + off); off += (size_t)B_PAT * NCH * 4 * sizeof(float2);   // 16 KB

  k1_features<<<B_PAT + 3, 256, 0, stream>>>(times, time_ptr, X, M, obs_idx,
                                             W0, b0, W1, b1, W2, b2, Wq, bq, Wk,
                                             feats, W0p, W1b, W2b, lens, r_all);
  k2_fused<<<B_PAT * NCH, 256, 0, stream>>>(feats, W0p, b0, W1b, b1, W2b, b2,
                                            lens, r_all, partial, mxsm);
  k4_combine<<<B_PAT, 256, 0, stream>>>(partial, mxsm, out);
}